// Round 3
// baseline (207.105 us; speedup 1.0000x reference)
//
#include <hip/hip_runtime.h>

typedef unsigned long long u64;
typedef unsigned int u32;

static constexpr int NF = 17;      // features per point
static constexpr int BCOL = 9;     // beta column
static constexpr int CCOL = 14;    // first ccoord column (17-3)
static constexpr int CONDCAP = 256;
static constexpr int NPASS = 2;    // grid-wide NMS rounds before k_finish
static constexpr int RPB = 512;    // rows per block in k_filter
static constexpr int MAXIT = 8;    // per-thread iters in k_pass (8*32*256 = 65536 = P)
static constexpr int CHK = 8;      // k_finish chunk size (items/thread/chunk)

#define T_B_F ((float)0.2)         // matches numpy float32(0.2)
#define R2_F  ((float)(0.7*0.7))   // matches numpy promotion of 0.48999999999999994

__device__ __forceinline__ u64 kmax(u64 a, u64 b){ return a > b ? a : b; }

__device__ __forceinline__ u64 shfl_down_u64(u64 v, int off){
    u32 lo = (u32)v, hi = (u32)(v >> 32);
    lo = __shfl_down(lo, off, 64);
    hi = __shfl_down(hi, off, 64);
    return ((u64)hi << 32) | lo;
}

__device__ __forceinline__ u64 waveReduceMax(u64 k){
    #pragma unroll
    for (int off = 32; off > 0; off >>= 1){
        u64 o = shfl_down_u64(k, off);
        if (o > k) k = o;
    }
    return k;
}

// distance with NO fp contraction — must match numpy (mul,mul,mul,add,add)
__device__ __forceinline__ float dist2(float cx, float cy, float cz,
                                       float rx, float ry, float rz){
    #pragma clang fp contract(off)
    float dx = cx - rx, dy = cy - ry, dz = cz - rz;
    float sx = dx * dx, sy = dy * dy, sz = dz * dz;
    return (sx + sy) + sz;
}

__device__ __forceinline__ u64 makeKey(float beta, u32 idx){
    return ((u64)__float_as_uint(beta) << 32) | (u64)(0xFFFFFFFFu - idx);
}

// ---------------- kernel 0: zero control block (4 KB) ----------------
__global__ void k_init(u32* ws){
    int t = threadIdx.x;
    if (t < 1024) ws[t] = 0;   // argmax[NPASS+1][E], cnt[NPASS+1][E], ncond[E], done
}

// ---------------- kernel 1: zero dout + filter + per-event argmax -------------
// Stage ONLY (cx,cy,cz,beta) through LDS (8 KB) -> occupancy-limited by waves.
__global__ __launch_bounds__(256) void k_filter(
    const float4* __restrict__ x4, float4* __restrict__ out4,
    u64* __restrict__ argmax0, int* __restrict__ cnt0,
    float4* __restrict__ cA, int* __restrict__ iA,
    int P, int chunksPerEvent)
{
    __shared__ float4 lrow[RPB];              // (cx,cy,cz,beta) per row — 8 KB
    __shared__ int swc[4], swb[4], sbase;
    __shared__ u64 sred[4];

    int e = blockIdx.x / chunksPerEvent;
    int chunk = blockIdx.x % chunksPerEvent;
    int rowStart = chunk * RPB;
    size_t tile4 = (size_t)blockIdx.x * (RPB * NF / 4);   // 2176 float4 per tile

    const int N4 = RPB * NF / 4;
    float4 z = make_float4(0.f, 0.f, 0.f, 0.f);
    for (int i = threadIdx.x; i < N4; i += 256){
        float4 v = x4[tile4 + i];
        out4[tile4 + i] = z;                   // fused zero of dout
        float vv[4] = {v.x, v.y, v.z, v.w};
        int f0 = 4 * i;
        #pragma unroll
        for (int j = 0; j < 4; j++){
            int flat = f0 + j;
            int row = flat / NF;               // magic-mul
            int col = flat - row * NF;
            if (col == BCOL)       ((float*)&lrow[row])[3] = vv[j];
            else if (col >= CCOL)  ((float*)&lrow[row])[col - CCOL] = vv[j];
        }
    }
    __syncthreads();

    int tid = threadIdx.x, lid = tid & 63, wid = tid >> 6;
    float4 a0 = lrow[tid], a1 = lrow[tid + 256];
    bool k0 = (a0.w >= T_B_F), k1 = (a1.w >= T_B_F);
    u64 bal0 = __ballot(k0), bal1 = __ballot(k1);
    int wcnt = __popcll(bal0) + __popcll(bal1);

    u64 lk = 0;
    if (k0) lk = makeKey(a0.w, (u32)(rowStart + tid));
    if (k1) lk = kmax(lk, makeKey(a1.w, (u32)(rowStart + tid + 256)));
    u64 kw = waveReduceMax(lk);
    if (lid == 0){ swc[wid] = wcnt; sred[wid] = kw; }
    __syncthreads();
    if (tid == 0){
        int tot = 0;
        for (int w = 0; w < 4; w++){ swb[w] = tot; tot += swc[w]; }
        sbase = tot ? atomicAdd(&cnt0[e], tot) : 0;      // 1 returning atomic / block
        u64 m = sred[0];
        for (int i = 1; i < 4; i++) m = kmax(m, sred[i]);
        if (m) atomicMax(&argmax0[e], m);                // fire-and-forget
    }
    __syncthreads();
    int base = sbase + swb[wid];
    u64 lm = (1ull << lid) - 1;
    size_t eoff = (size_t)e * P;
    if (k0){
        int pos = base + __popcll(bal0 & lm);
        cA[eoff + pos] = a0;
        iA[eoff + pos] = rowStart + tid;
    }
    if (k1){
        int pos = base + __popcll(bal0) + __popcll(bal1 & lm);
        cA[eoff + pos] = a1;
        iA[eoff + pos] = rowStart + tid + 256;
    }
}

// ---------------- kernel 2: one grid-wide NMS round; ONE atomic per block -----
__global__ __launch_bounds__(256) void k_pass(
    const float* __restrict__ x,
    const float4* __restrict__ cIn, const int* __restrict__ iIn,
    float4* __restrict__ cOut, int* __restrict__ iOut,
    const u64* __restrict__ argmaxIn, u64* __restrict__ argmaxOut,
    const int* __restrict__ cntIn, int* __restrict__ cntOut,
    int* __restrict__ ncond, int* __restrict__ condlist,
    int P, int blocksPerEvent)
{
    __shared__ int swc[4], swb[4], sbase;
    __shared__ u64 sred[4];

    int e = blockIdx.x / blocksPerEvent;
    int c = blockIdx.x % blocksPerEvent;
    u64 key = argmaxIn[e];
    float betaRef = __uint_as_float((u32)(key >> 32));
    if (!(betaRef >= T_B_F)) return;   // event finished (uniform across its blocks)
    u32 refIdx = 0xFFFFFFFFu - (u32)(key & 0xFFFFFFFFu);
    if (c == 0 && threadIdx.x == 0){
        int s = atomicAdd(&ncond[e], 1);
        if (s < CONDCAP) condlist[e * CONDCAP + s] = (int)refIdx;
    }
    size_t rbase = ((size_t)e * P + refIdx) * NF;
    float rx = x[rbase + CCOL], ry = x[rbase + CCOL + 1], rz = x[rbase + CCOL + 2];

    int n = cntIn[e];
    int tid = threadIdx.x, lid = tid & 63, wid = tid >> 6;
    size_t eoff = (size_t)e * P;
    int stride = blocksPerEvent * 256;

    float4 cc[MAXIT]; int ix[MAXIT]; bool kp[MAXIT]; u64 bal[MAXIT];
    int wcnt = 0;
    u64 lk = 0;
    #pragma unroll
    for (int k = 0; k < MAXIT; k++){
        int i = c * 256 + tid + k * stride;
        bool inb = i < n;
        int ii = inb ? i : 0;
        cc[k] = cIn[eoff + ii];
        ix[k] = iIn[eoff + ii];
        float d2 = dist2(cc[k].x, cc[k].y, cc[k].z, rx, ry, rz);
        kp[k] = inb && !(d2 <= R2_F);
        bal[k] = __ballot(kp[k]);
        wcnt += __popcll(bal[k]);
        if (kp[k]) lk = kmax(lk, makeKey(cc[k].w, (u32)ix[k]));
    }
    u64 kw = waveReduceMax(lk);
    if (lid == 0){ swc[wid] = wcnt; sred[wid] = kw; }
    __syncthreads();
    if (tid == 0){
        int tot = 0;
        for (int w = 0; w < 4; w++){ swb[w] = tot; tot += swc[w]; }
        sbase = tot ? atomicAdd(&cntOut[e], tot) : 0;
        u64 m = sred[0];
        for (int i = 1; i < 4; i++) m = kmax(m, sred[i]);
        if (m) atomicMax(&argmaxOut[e], m);
    }
    __syncthreads();
    int pos = sbase + swb[wid];
    u64 lm = (1ull << lid) - 1;
    #pragma unroll
    for (int k = 0; k < MAXIT; k++){
        if (kp[k]){
            int p_ = pos + __popcll(bal[k] & lm);
            cOut[eoff + p_] = cc[k];
            iOut[eoff + p_] = ix[k];
        }
        pos += __popcll(bal[k]);
    }
}

// ---------------- kernel 3: per-event finish + scatter + splits ---------------
// One block/event. Chunked two-phase compaction (1 LDS atomic / wave / chunk).
// Argmax reduction carries the winner's coords as payload (no ref-row reload).
// Last block to finish writes out_row_splits (device-scope done counter).
__global__ __launch_bounds__(1024) void k_finish(
    const float* __restrict__ x, float* __restrict__ out,
    float4* cA, int* iA, float4* cB, int* iB,
    const u64* __restrict__ argmaxN, const int* __restrict__ cntN,
    int* __restrict__ ncond, int* __restrict__ condlist,
    int* __restrict__ done, int P, int E)
{
    int e = blockIdx.x;
    __shared__ u64 skey16[16];
    __shared__ float4 spay16[16];
    __shared__ int scnt, sNC, sLast;
    __shared__ u64 skey;
    __shared__ float srefc[3];

    int tid = threadIdx.x, lid = tid & 63, wid = tid >> 6;
    int n = cntN[e];
    u64 key = argmaxN[e];
    float4* cIn = cA + (size_t)e * P; int* iIn = iA + (size_t)e * P;
    float4* cOut = cB + (size_t)e * P; int* iOut = iB + (size_t)e * P;
    bool havePay = false;

    while (true){
        float betaRef = __uint_as_float((u32)(key >> 32));
        if (!(betaRef >= T_B_F)) break;          // uniform decision
        u32 refIdx = 0xFFFFFFFFu - (u32)(key & 0xFFFFFFFFu);
        if (tid == 0){
            int s = atomicAdd(&ncond[e], 1);
            if (s < CONDCAP) condlist[e * CONDCAP + s] = (int)refIdx;
            if (!havePay){                        // first round: load ref coords
                size_t rb = ((size_t)e * P + refIdx) * NF;
                srefc[0] = x[rb + CCOL];
                srefc[1] = x[rb + CCOL + 1];
                srefc[2] = x[rb + CCOL + 2];
            }
            scnt = 0;
        }
        havePay = true;
        __syncthreads();                          // (A)
        float rx = srefc[0], ry = srefc[1], rz = srefc[2];

        u64 bk = 0; float bx = 0.f, by = 0.f, bz = 0.f;
        for (int base = 0; base < n; base += 1024 * CHK){
            float4 cc[CHK]; int ix[CHK]; bool kp[CHK]; u64 bal[CHK];
            int wcnt = 0;
            #pragma unroll
            for (int k = 0; k < CHK; k++){
                int i = base + k * 1024 + tid;
                bool inb = i < n;
                int ii = inb ? i : 0;
                cc[k] = cIn[ii];
                ix[k] = iIn[ii];
                float d2 = dist2(cc[k].x, cc[k].y, cc[k].z, rx, ry, rz);
                kp[k] = inb && !(d2 <= R2_F);
                bal[k] = __ballot(kp[k]);
                wcnt += __popcll(bal[k]);
                if (kp[k]){
                    u64 mk = makeKey(cc[k].w, (u32)ix[k]);
                    if (mk > bk){ bk = mk; bx = cc[k].x; by = cc[k].y; bz = cc[k].z; }
                }
            }
            int wbase = 0;
            if (lid == 0) wbase = wcnt ? atomicAdd(&scnt, wcnt) : 0;
            wbase = __shfl(wbase, 0, 64);
            u64 lm = (1ull << lid) - 1;
            #pragma unroll
            for (int k = 0; k < CHK; k++){
                if (kp[k]){
                    int p_ = wbase + __popcll(bal[k] & lm);
                    cOut[p_] = cc[k];
                    iOut[p_] = ix[k];
                }
                wbase += __popcll(bal[k]);
            }
        }
        // wave-level argmax with coord payload
        #pragma unroll
        for (int off = 32; off > 0; off >>= 1){
            u64 ok = shfl_down_u64(bk, off);
            float ox = __shfl_down(bx, off, 64);
            float oy = __shfl_down(by, off, 64);
            float oz = __shfl_down(bz, off, 64);
            if (ok > bk){ bk = ok; bx = ox; by = oy; bz = oz; }
        }
        if (lid == 0){ skey16[wid] = bk; spay16[wid] = make_float4(bx, by, bz, 0.f); }
        __syncthreads();                          // (B)
        if (tid == 0){
            u64 m = 0; float4 pp = make_float4(0.f, 0.f, 0.f, 0.f);
            for (int i = 0; i < 16; i++)
                if (skey16[i] > m){ m = skey16[i]; pp = spay16[i]; }
            skey = m;
            srefc[0] = pp.x; srefc[1] = pp.y; srefc[2] = pp.z;
        }
        __syncthreads();                          // (C)
        key = skey;
        n = scnt;
        { float4* t = cIn; cIn = cOut; cOut = t; }
        { int* t = iIn; iIn = iOut; iOut = t; }
        __syncthreads();                          // (D)
    }

    // scatter this event's condensate rows (zero-fill already done by k_filter)
    if (tid == 0) sNC = atomicAdd(&ncond[e], 0);
    __syncthreads();
    int nc = sNC; if (nc > CONDCAP) nc = CONDCAP;
    for (int i = tid; i < nc * NF; i += 1024){
        int j = i / NF, f = i - j * NF;
        int row = condlist[e * CONDCAP + j];
        size_t b = ((size_t)e * P + row) * NF;
        out[b + f] = x[b + f];
    }

    // last finishing block writes out_row_splits (as float32)
    __threadfence();
    if (tid == 0) sLast = atomicAdd(done, 1);
    __syncthreads();
    if (sLast == E - 1 && tid == 0){
        size_t so = (size_t)E * P * NF;
        int s = 0;
        out[so] = 0.f;
        for (int i = 0; i < E; i++){
            s += atomicAdd(&ncond[i], 0);   // device-coherent read
            out[so + i + 1] = (float)s;
        }
    }
}

extern "C" void kernel_launch(void* const* d_in, const int* in_sizes, int n_in,
                              void* d_out, int out_size, void* d_ws, size_t ws_size,
                              hipStream_t stream) {
    const float* x = (const float*)d_in[0];
    int N = in_sizes[0] / NF;
    int E = in_sizes[1] - 1;
    int P = N / E;
    float* out = (float*)d_out;
    char* ws = (char*)d_ws;

    // ws layout (first 4 KB zeroed by k_init)
    u64* argmax = (u64*)ws;                         // [NPASS+1][E]
    int* cnt    = (int*)(ws + 1024);                // [NPASS+1][E]
    int* ncond  = (int*)(ws + 2048);                // [E]
    int* done   = (int*)(ws + 2560);                // [1]
    int* condlist = (int*)(ws + 4096);              // [E][CONDCAP] = 16 KB
    size_t listOff = 32768;
    size_t listElems = (size_t)E * P;
    float4* cA = (float4*)(ws + listOff);
    float4* cB = (float4*)(ws + listOff + listElems * 16);
    int* iA = (int*)(ws + listOff + listElems * 32);
    int* iB = (int*)(ws + listOff + listElems * 36);

    k_init<<<1, 1024, 0, stream>>>((u32*)ws);

    int chunksPerEvent = P / RPB;                   // 128
    k_filter<<<E * chunksPerEvent, 256, 0, stream>>>(
        (const float4*)x, (float4*)out, argmax, cnt, cA, iA, P, chunksPerEvent);

    int bpe = 32;                                   // 32*256*MAXIT = 65536 = P coverage
    float4* cs[2] = {cA, cB};
    int* is[2] = {iA, iB};
    for (int r = 0; r < NPASS; r++){
        k_pass<<<E * bpe, 256, 0, stream>>>(
            x, cs[r & 1], is[r & 1], cs[(r + 1) & 1], is[(r + 1) & 1],
            argmax + r * E, argmax + (r + 1) * E,
            cnt + r * E, cnt + (r + 1) * E,
            ncond, condlist, P, bpe);
    }

    // NPASS even -> current list is back in cA
    k_finish<<<E, 1024, 0, stream>>>(
        x, out, cA, iA, cB, iB, argmax + NPASS * E, cnt + NPASS * E,
        ncond, condlist, done, P, E);
}